// Round 1
// baseline (809.925 us; speedup 1.0000x reference)
//
#include <hip/hip_runtime.h>

#define DIN 32
#define DOUT 32

// ---------------------------------------------------------------------------
// Kernel 1: degree counting. One thread per edge, int atomics.
// ---------------------------------------------------------------------------
__global__ void deg_kernel(const int* __restrict__ src, const int* __restrict__ dst,
                           int* __restrict__ degs, int* __restrict__ degd, int E) {
    int i = blockIdx.x * blockDim.x + threadIdx.x;
    if (i < E) {
        atomicAdd(&degs[src[i]], 1);
        atomicAdd(&degd[dst[i]], 1);
    }
}

// ---------------------------------------------------------------------------
// Kernel 2: h = (x * norm_src) @ W.   Block = 256 threads = 8 rows x 32 cols.
// W staged in LDS (padded), x rows staged in LDS.
// ---------------------------------------------------------------------------
__global__ void transform_kernel(const float* __restrict__ x, const float* __restrict__ W,
                                 const int* __restrict__ degs, float* __restrict__ h, int n) {
    __shared__ float Ws[32][33];
    __shared__ float xs[8][32];
    int col = threadIdx.x & 31;
    int r   = threadIdx.x >> 5;  // 0..7

    // load W (1024 floats) cooperatively
    for (int i = threadIdx.x; i < 32 * 32; i += 256) {
        Ws[i >> 5][i & 31] = W[i];
    }
    int row = blockIdx.x * 8 + r;
    xs[r][col] = (row < n) ? x[row * 32 + col] : 0.f;
    __syncthreads();

    if (row < n) {
        float acc = 0.f;
#pragma unroll
        for (int k = 0; k < 32; ++k) acc += xs[r][k] * Ws[k][col];
        int d = degs[row];
        float nrm = (d > 0) ? rsqrtf((float)d) : 0.f;
        h[row * 32 + col] = acc * nrm;
    }
}

// ---------------------------------------------------------------------------
// Kernel 3: scatter-add.  8 threads per edge; each thread: one float4 gather
// from h[src], four f32 atomicAdds into out[dst].
// ---------------------------------------------------------------------------
__global__ void scatter_kernel(const int* __restrict__ src, const int* __restrict__ dst,
                               const float* __restrict__ h, float* __restrict__ out, int E) {
    int t = blockIdx.x * blockDim.x + threadIdx.x;
    int e = t >> 3;  // edge index
    int q = t & 7;   // which float4 of the 32-float row
    if (e < E) {
        int s = src[e];
        int d = dst[e];
        const float4 v = *reinterpret_cast<const float4*>(&h[s * 32 + q * 4]);
        float* o = &out[d * 32 + q * 4];
        atomicAdd(o + 0, v.x);
        atomicAdd(o + 1, v.y);
        atomicAdd(o + 2, v.z);
        atomicAdd(o + 3, v.w);
    }
}

// ---------------------------------------------------------------------------
// Kernel 4: out = out * norm_dst + b
// ---------------------------------------------------------------------------
__global__ void finalize_kernel(float* __restrict__ out, const int* __restrict__ degd,
                                const float* __restrict__ b, int n) {
    int t = blockIdx.x * blockDim.x + threadIdx.x;
    if (t < n * 32) {
        int row = t >> 5;
        int col = t & 31;
        int d = degd[row];
        float nrm = (d > 0) ? rsqrtf((float)d) : 0.f;
        out[t] = out[t] * nrm + b[col];
    }
}

extern "C" void kernel_launch(void* const* d_in, const int* in_sizes, int n_in,
                              void* d_out, int out_size, void* d_ws, size_t ws_size,
                              hipStream_t stream) {
    const float* x  = (const float*)d_in[0];
    const int*   ei = (const int*)d_in[1];
    const float* W  = (const float*)d_in[2];
    const float* b  = (const float*)d_in[3];
    float* out = (float*)d_out;

    const int n = in_sizes[0] / DIN;   // 100000
    const int E = in_sizes[1] / 2;     // 1600000

    // workspace layout: degs[n] int | degd[n] int | h[n*32] float  (~13.6 MB)
    int*   degs = (int*)d_ws;
    int*   degd = degs + n;
    float* h    = (float*)(degd + n);

    const int* src = ei;
    const int* dst = ei + E;

    hipMemsetAsync(d_ws, 0, (size_t)2 * n * sizeof(int), stream);
    hipMemsetAsync(d_out, 0, (size_t)out_size * sizeof(float), stream);

    deg_kernel<<<(E + 255) / 256, 256, 0, stream>>>(src, dst, degs, degd, E);
    transform_kernel<<<(n + 7) / 8, 256, 0, stream>>>(x, W, degs, h, n);

    long long st = (long long)E * 8;
    scatter_kernel<<<(int)((st + 255) / 256), 256, 0, stream>>>(src, dst, h, out, E);

    finalize_kernel<<<(n * 32 + 255) / 256, 256, 0, stream>>>(out, degd, b, n);
}

// Round 2
// 326.256 us; speedup vs baseline: 2.4825x; 2.4825x over previous
//
#include <hip/hip_runtime.h>

#define DIN 32
#define DOUT 32

// ---------------------------------------------------------------------------
// Kernel 1: degree counting. One thread per edge, int atomics.
// ---------------------------------------------------------------------------
__global__ void deg_kernel(const int* __restrict__ src, const int* __restrict__ dst,
                           int* __restrict__ degs, int* __restrict__ degd, int E) {
    int i = blockIdx.x * blockDim.x + threadIdx.x;
    if (i < E) {
        atomicAdd(&degs[src[i]], 1);
        atomicAdd(&degd[dst[i]], 1);
    }
}

// ---------------------------------------------------------------------------
// Kernel 2: h = (x * norm_src) @ W.   Block = 256 threads = 8 rows x 32 cols.
// ---------------------------------------------------------------------------
__global__ void transform_kernel(const float* __restrict__ x, const float* __restrict__ W,
                                 const int* __restrict__ degs, float* __restrict__ h, int n) {
    __shared__ float Ws[32][33];
    __shared__ float xs[8][32];
    int col = threadIdx.x & 31;
    int r   = threadIdx.x >> 5;  // 0..7

    for (int i = threadIdx.x; i < 32 * 32; i += 256) {
        Ws[i >> 5][i & 31] = W[i];
    }
    int row = blockIdx.x * 8 + r;
    xs[r][col] = (row < n) ? x[row * 32 + col] : 0.f;
    __syncthreads();

    if (row < n) {
        float acc = 0.f;
#pragma unroll
        for (int k = 0; k < 32; ++k) acc += xs[r][k] * Ws[k][col];
        int d = degs[row];
        float nrm = (d > 0) ? rsqrtf((float)d) : 0.f;
        h[row * 32 + col] = acc * nrm;
    }
}

// ---------------------------------------------------------------------------
// Exclusive scan of degd -> offs (3 phases). 1024 elements per scan block.
// ---------------------------------------------------------------------------
#define SCAN_T 256
#define SCAN_I 4
__global__ void scan1_kernel(const int* __restrict__ degd, int* __restrict__ offs,
                             int* __restrict__ bsums, int n) {
    __shared__ int lds[SCAN_T];
    int base = blockIdx.x * (SCAN_T * SCAN_I) + threadIdx.x * SCAN_I;
    int v[SCAN_I];
    int tsum = 0;
#pragma unroll
    for (int i = 0; i < SCAN_I; ++i) {
        int idx = base + i;
        v[i] = (idx < n) ? degd[idx] : 0;
        tsum += v[i];
    }
    lds[threadIdx.x] = tsum;
    for (int off = 1; off < SCAN_T; off <<= 1) {
        __syncthreads();
        int y = (threadIdx.x >= off) ? lds[threadIdx.x - off] : 0;
        __syncthreads();
        lds[threadIdx.x] += y;
    }
    __syncthreads();
    int excl = lds[threadIdx.x] - tsum;  // exclusive prefix of thread sums
    int run = excl;
#pragma unroll
    for (int i = 0; i < SCAN_I; ++i) {
        int idx = base + i;
        if (idx < n) offs[idx] = run;
        run += v[i];
    }
    if (threadIdx.x == SCAN_T - 1) bsums[blockIdx.x] = run;  // block total
}

__global__ void scan2_kernel(int* __restrict__ bsums, int B) {
    __shared__ int lds[1024];
    int t = threadIdx.x;
    int v = (t < B) ? bsums[t] : 0;
    lds[t] = v;
    for (int off = 1; off < 1024; off <<= 1) {
        __syncthreads();
        int y = (t >= off) ? lds[t - off] : 0;
        __syncthreads();
        lds[t] += y;
    }
    __syncthreads();
    if (t < B) bsums[t] = lds[t] - v;  // exclusive
}

__global__ void scan3_kernel(int* __restrict__ offs, const int* __restrict__ bsums,
                             int* __restrict__ cursor, int n, int E) {
    int i = blockIdx.x * blockDim.x + threadIdx.x;
    if (i < n) {
        int o = offs[i] + bsums[i >> 10];  // 1024 items per scan1 block
        offs[i] = o;
        cursor[i] = o;
    }
    if (i == 0) offs[n] = E;
}

// ---------------------------------------------------------------------------
// Bucket fill: esrc[pos] = src, grouped by dst. Int atomics only.
// ---------------------------------------------------------------------------
__global__ void fill_kernel(const int* __restrict__ src, const int* __restrict__ dst,
                            int* __restrict__ cursor, int* __restrict__ esrc, int E) {
    int e = blockIdx.x * blockDim.x + threadIdx.x;
    if (e < E) {
        int p = atomicAdd(&cursor[dst[e]], 1);
        esrc[p] = src[e];
    }
}

// ---------------------------------------------------------------------------
// Aggregate: one wave (64 lanes) per dst node. 32 lanes = 32 features,
// 2 halves x 2-way unroll = 4 independent gather streams. Fused finalize.
// ---------------------------------------------------------------------------
__global__ void aggregate_kernel(const int* __restrict__ offs, const int* __restrict__ esrc,
                                 const float* __restrict__ h, const float* __restrict__ b,
                                 float* __restrict__ out, int n) {
    int node = (blockIdx.x * blockDim.x + threadIdx.x) >> 6;
    if (node >= n) return;
    int lane = threadIdx.x & 63;
    int j    = lane & 31;
    int half = lane >> 5;

    int beg = offs[node];
    int end = offs[node + 1];

    float a0 = 0.f, a1 = 0.f;
    int k = beg + half;
    for (; k + 2 < end; k += 4) {
        int s0 = esrc[k];
        int s1 = esrc[k + 2];
        a0 += h[s0 * 32 + j];
        a1 += h[s1 * 32 + j];
    }
    if (k < end) a0 += h[esrc[k] * 32 + j];

    float acc = a0 + a1;
    acc += __shfl_xor(acc, 32);  // combine halves

    if (half == 0) {
        int d = end - beg;
        float nrm = (d > 0) ? rsqrtf((float)d) : 0.f;
        out[node * 32 + j] = acc * nrm + b[j];
    }
}

// ---------------------------------------------------------------------------
// Fallback path (atomic scatter), used only if ws_size is too small for CSR.
// ---------------------------------------------------------------------------
__global__ void scatter_kernel(const int* __restrict__ src, const int* __restrict__ dst,
                               const float* __restrict__ h, float* __restrict__ out, int E) {
    int t = blockIdx.x * blockDim.x + threadIdx.x;
    int e = t >> 3;
    int q = t & 7;
    if (e < E) {
        int s = src[e];
        int d = dst[e];
        const float4 v = *reinterpret_cast<const float4*>(&h[s * 32 + q * 4]);
        float* o = &out[d * 32 + q * 4];
        atomicAdd(o + 0, v.x);
        atomicAdd(o + 1, v.y);
        atomicAdd(o + 2, v.z);
        atomicAdd(o + 3, v.w);
    }
}

__global__ void finalize_kernel(float* __restrict__ out, const int* __restrict__ degd,
                                const float* __restrict__ b, int n) {
    int t = blockIdx.x * blockDim.x + threadIdx.x;
    if (t < n * 32) {
        int row = t >> 5;
        int col = t & 31;
        int d = degd[row];
        float nrm = (d > 0) ? rsqrtf((float)d) : 0.f;
        out[t] = out[t] * nrm + b[col];
    }
}

extern "C" void kernel_launch(void* const* d_in, const int* in_sizes, int n_in,
                              void* d_out, int out_size, void* d_ws, size_t ws_size,
                              hipStream_t stream) {
    const float* x  = (const float*)d_in[0];
    const int*   ei = (const int*)d_in[1];
    const float* W  = (const float*)d_in[2];
    const float* b  = (const float*)d_in[3];
    float* out = (float*)d_out;

    const int n = in_sizes[0] / DIN;   // 100000
    const int E = in_sizes[1] / 2;     // 1600000

    const int* src = ei;
    const int* dst = ei + E;

    // workspace layout (h first for 16B alignment):
    // h[n*32] f32 | degs[n] | degd[n] | offs[n+1] | cursor[n] | esrc[E] | bsums[1024]
    float* h      = (float*)d_ws;
    int*   degs   = (int*)(h + (size_t)n * 32);
    int*   degd   = degs + n;
    int*   offs   = degd + n;
    int*   cursor = offs + n + 1;
    int*   esrc   = cursor + n;
    int*   bsums  = esrc + E;
    size_t needed = (size_t)((char*)(bsums + 1024) - (char*)d_ws);

    hipMemsetAsync(degs, 0, (size_t)2 * n * sizeof(int), stream);
    deg_kernel<<<(E + 255) / 256, 256, 0, stream>>>(src, dst, degs, degd, E);
    transform_kernel<<<(n + 7) / 8, 256, 0, stream>>>(x, W, degs, h, n);

    const int B = (n + SCAN_T * SCAN_I - 1) / (SCAN_T * SCAN_I);  // scan blocks (98)

    if (ws_size >= needed && B <= 1024) {
        // CSR path: no float atomics.
        scan1_kernel<<<B, SCAN_T, 0, stream>>>(degd, offs, bsums, n);
        scan2_kernel<<<1, 1024, 0, stream>>>(bsums, B);
        scan3_kernel<<<(n + 255) / 256, 256, 0, stream>>>(offs, bsums, cursor, n, E);
        fill_kernel<<<(E + 255) / 256, 256, 0, stream>>>(src, dst, cursor, esrc, E);
        aggregate_kernel<<<(n * 64 + 255) / 256, 256, 0, stream>>>(offs, esrc, h, b, out, n);
    } else {
        // Fallback: atomic scatter.
        hipMemsetAsync(d_out, 0, (size_t)out_size * sizeof(float), stream);
        long long st = (long long)E * 8;
        scatter_kernel<<<(int)((st + 255) / 256), 256, 0, stream>>>(src, dst, h, out, E);
        finalize_kernel<<<(n * 32 + 255) / 256, 256, 0, stream>>>(out, degd, b, n);
    }
}

// Round 3
// 190.548 us; speedup vs baseline: 4.2505x; 1.7122x over previous
//
#include <hip/hip_runtime.h>

#define DIN 32
#define DOUT 32
#define NBMAX 256     // max coarse bins
#define BINSHIFT 9    // 512 nodes per bin
#define BINW 512
#define PK 16         // edges per thread in partition kernels (block covers 4096)

// ---------------------------------------------------------------------------
// Coarse histograms of src and dst (bin = key >> BINSHIFT) in one read pass.
// LDS-privatized; ~256 global atomics per block (line-disjoint, cheap).
// ---------------------------------------------------------------------------
__global__ void hist_coarse_kernel(const int* __restrict__ src, const int* __restrict__ dst,
                                   int E, int* __restrict__ gcntS, int* __restrict__ gcntD) {
    __shared__ int hS[NBMAX], hD[NBMAX];
    for (int i = threadIdx.x; i < NBMAX; i += 256) { hS[i] = 0; hD[i] = 0; }
    __syncthreads();
    int stride = gridDim.x * blockDim.x;
    for (int e = blockIdx.x * blockDim.x + threadIdx.x; e < E; e += stride) {
        atomicAdd(&hS[src[e] >> BINSHIFT], 1);
        atomicAdd(&hD[dst[e] >> BINSHIFT], 1);
    }
    __syncthreads();
    for (int i = threadIdx.x; i < NBMAX; i += 256) {
        if (hS[i]) atomicAdd(&gcntS[i], hS[i]);
        if (hD[i]) atomicAdd(&gcntD[i], hD[i]);
    }
}

// ---------------------------------------------------------------------------
// Exclusive scan of both coarse histograms (single block). Also inits cursors
// and writes offs[n] = E.
// ---------------------------------------------------------------------------
__global__ void scan_coarse_kernel(const int* __restrict__ gcntS, const int* __restrict__ gcntD,
                                   int* __restrict__ baseS, int* __restrict__ baseD,
                                   int* __restrict__ curS, int* __restrict__ curD,
                                   int* __restrict__ offs, int NB, int n, int E) {
    __shared__ int s1[256], s2[256];
    int t = threadIdx.x;
    int a = (t < NB) ? gcntS[t] : 0;
    int c = (t < NB) ? gcntD[t] : 0;
    s1[t] = a; s2[t] = c;
    for (int o = 1; o < 256; o <<= 1) {
        __syncthreads();
        int x = (t >= o) ? s1[t - o] : 0;
        int y = (t >= o) ? s2[t - o] : 0;
        __syncthreads();
        s1[t] += x; s2[t] += y;
    }
    __syncthreads();
    if (t < NB) {
        baseS[t] = s1[t] - a; curS[t] = s1[t] - a;
        baseD[t] = s2[t] - c; curD[t] = s2[t] - c;
    }
    if (t == 0) { baseS[NB] = E; baseD[NB] = E; offs[n] = E; }
}

// ---------------------------------------------------------------------------
// Partition src values into coarse bins (key = payload = src).
// Rank within (block,bin) via LDS atomics; one global atomic per (block,bin).
// ---------------------------------------------------------------------------
__global__ void partitionS_kernel(const int* __restrict__ src, int E,
                                  int* __restrict__ curS, int* __restrict__ binned) {
    __shared__ int cnt[NBMAX];
    __shared__ int base[NBMAX];
    for (int i = threadIdx.x; i < NBMAX; i += 256) cnt[i] = 0;
    __syncthreads();
    int base_e = blockIdx.x * (256 * PK);
    int v[PK], rk[PK];
#pragma unroll
    for (int i = 0; i < PK; ++i) {
        int e = base_e + i * 256 + threadIdx.x;
        if (e < E) { v[i] = src[e]; rk[i] = atomicAdd(&cnt[v[i] >> BINSHIFT], 1); }
        else v[i] = -1;
    }
    __syncthreads();
    for (int i = threadIdx.x; i < NBMAX; i += 256) {
        int c = cnt[i];
        base[i] = c ? atomicAdd(&curS[i], c) : 0;
    }
    __syncthreads();
#pragma unroll
    for (int i = 0; i < PK; ++i)
        if (v[i] >= 0) binned[base[v[i] >> BINSHIFT] + rk[i]] = v[i];
}

// ---------------------------------------------------------------------------
// Partition (dst,src) pairs into coarse bins keyed by dst.
// ---------------------------------------------------------------------------
__global__ void partitionD_kernel(const int* __restrict__ src, const int* __restrict__ dst,
                                  int E, int* __restrict__ curD, int2* __restrict__ binned) {
    __shared__ int cnt[NBMAX];
    __shared__ int base[NBMAX];
    for (int i = threadIdx.x; i < NBMAX; i += 256) cnt[i] = 0;
    __syncthreads();
    int base_e = blockIdx.x * (256 * PK);
    int vd[PK], vs[PK], rk[PK];
#pragma unroll
    for (int i = 0; i < PK; ++i) {
        int e = base_e + i * 256 + threadIdx.x;
        if (e < E) {
            vd[i] = dst[e]; vs[i] = src[e];
            rk[i] = atomicAdd(&cnt[vd[i] >> BINSHIFT], 1);
        } else vd[i] = -1;
    }
    __syncthreads();
    for (int i = threadIdx.x; i < NBMAX; i += 256) {
        int c = cnt[i];
        base[i] = c ? atomicAdd(&curD[i], c) : 0;
    }
    __syncthreads();
#pragma unroll
    for (int i = 0; i < PK; ++i)
        if (vd[i] >= 0) {
            int2 p; p.x = vd[i]; p.y = vs[i];
            binned[base[vd[i] >> BINSHIFT] + rk[i]] = p;
        }
}

// ---------------------------------------------------------------------------
// Per-bin src-degree count (LDS counters, bin spans 512 nodes).
// ---------------------------------------------------------------------------
__global__ void bin_count_src_kernel(const int* __restrict__ binned, const int* __restrict__ baseS,
                                     int* __restrict__ degs, int n) {
    __shared__ int cnt[BINW];
    int b = blockIdx.x;
    int beg = baseS[b], end = baseS[b + 1];
    int lo = b << BINSHIFT;
    int t = threadIdx.x;
    cnt[t] = 0; cnt[t + 256] = 0;
    __syncthreads();
    for (int e = beg + t; e < end; e += 256) atomicAdd(&cnt[binned[e] - lo], 1);
    __syncthreads();
    for (int i = t; i < BINW; i += 256) {
        int node = lo + i;
        if (node < n) degs[node] = cnt[i];
    }
}

// ---------------------------------------------------------------------------
// Per-bin CSR: count per node (LDS), LDS scan (512), write offs, scatter esrc.
// ---------------------------------------------------------------------------
__global__ void bin_csr_kernel(const int2* __restrict__ binned, const int* __restrict__ baseD,
                               int* __restrict__ offs, int* __restrict__ esrc, int n) {
    __shared__ int cnt[BINW];
    __shared__ int pscan[256];
    int b = blockIdx.x;
    int beg = baseD[b], end = baseD[b + 1];
    int lo = b << BINSHIFT;
    int t = threadIdx.x;
    cnt[t] = 0; cnt[t + 256] = 0;
    __syncthreads();
    for (int e = beg + t; e < end; e += 256) atomicAdd(&cnt[binned[e].x - lo], 1);
    __syncthreads();
    int c0 = cnt[2 * t], c1 = cnt[2 * t + 1];
    int pair = c0 + c1;
    pscan[t] = pair;
    for (int o = 1; o < 256; o <<= 1) {
        __syncthreads();
        int x = (t >= o) ? pscan[t - o] : 0;
        __syncthreads();
        pscan[t] += x;
    }
    __syncthreads();
    int excl = pscan[t] - pair;       // exclusive prefix over pairs
    int off0 = excl, off1 = excl + c0;
    int n0 = lo + 2 * t, n1 = n0 + 1;
    if (n0 < n) offs[n0] = beg + off0;
    if (n1 < n) offs[n1] = beg + off1;
    cnt[2 * t] = off0; cnt[2 * t + 1] = off1;   // become cursors
    __syncthreads();
    for (int e = beg + t; e < end; e += 256) {
        int2 p = binned[e];
        int r = atomicAdd(&cnt[p.x - lo], 1);
        esrc[beg + r] = p.y;
    }
}

// ---------------------------------------------------------------------------
// h = (x * norm_src) @ W.   Block = 256 threads = 8 rows x 32 cols.
// ---------------------------------------------------------------------------
__global__ void transform_kernel(const float* __restrict__ x, const float* __restrict__ W,
                                 const int* __restrict__ degs, float* __restrict__ h, int n) {
    __shared__ float Ws[32][33];
    __shared__ float xs[8][32];
    int col = threadIdx.x & 31;
    int r   = threadIdx.x >> 5;

    for (int i = threadIdx.x; i < 32 * 32; i += 256) Ws[i >> 5][i & 31] = W[i];
    int row = blockIdx.x * 8 + r;
    xs[r][col] = (row < n) ? x[row * 32 + col] : 0.f;
    __syncthreads();

    if (row < n) {
        float acc = 0.f;
#pragma unroll
        for (int k = 0; k < 32; ++k) acc += xs[r][k] * Ws[k][col];
        int d = degs[row];
        float nrm = (d > 0) ? rsqrtf((float)d) : 0.f;
        h[row * 32 + col] = acc * nrm;
    }
}

// ---------------------------------------------------------------------------
// Aggregate: one wave per dst node, fused norm_dst + bias.
// ---------------------------------------------------------------------------
__global__ void aggregate_kernel(const int* __restrict__ offs, const int* __restrict__ esrc,
                                 const float* __restrict__ h, const float* __restrict__ b,
                                 float* __restrict__ out, int n) {
    int node = (blockIdx.x * blockDim.x + threadIdx.x) >> 6;
    if (node >= n) return;
    int lane = threadIdx.x & 63;
    int j    = lane & 31;
    int half = lane >> 5;

    int beg = offs[node];
    int end = offs[node + 1];

    float a0 = 0.f, a1 = 0.f;
    int k = beg + half;
    for (; k + 2 < end; k += 4) {
        int s0 = esrc[k];
        int s1 = esrc[k + 2];
        a0 += h[s0 * 32 + j];
        a1 += h[s1 * 32 + j];
    }
    if (k < end) a0 += h[esrc[k] * 32 + j];

    float acc = a0 + a1;
    acc += __shfl_xor(acc, 32);

    if (half == 0) {
        int d = end - beg;
        float nrm = (d > 0) ? rsqrtf((float)d) : 0.f;
        out[node * 32 + j] = acc * nrm + b[j];
    }
}

// ---------------------------------------------------------------------------
// Fallback (atomic) path kernels — only if workspace too small / n too large.
// ---------------------------------------------------------------------------
__global__ void deg_kernel(const int* __restrict__ src, const int* __restrict__ dst,
                           int* __restrict__ degs, int* __restrict__ degd, int E) {
    int i = blockIdx.x * blockDim.x + threadIdx.x;
    if (i < E) {
        atomicAdd(&degs[src[i]], 1);
        atomicAdd(&degd[dst[i]], 1);
    }
}

__global__ void scatter_kernel(const int* __restrict__ src, const int* __restrict__ dst,
                               const float* __restrict__ h, float* __restrict__ out, int E) {
    int t = blockIdx.x * blockDim.x + threadIdx.x;
    int e = t >> 3;
    int q = t & 7;
    if (e < E) {
        int s = src[e];
        int d = dst[e];
        const float4 v = *reinterpret_cast<const float4*>(&h[s * 32 + q * 4]);
        float* o = &out[d * 32 + q * 4];
        atomicAdd(o + 0, v.x);
        atomicAdd(o + 1, v.y);
        atomicAdd(o + 2, v.z);
        atomicAdd(o + 3, v.w);
    }
}

__global__ void finalize_kernel(float* __restrict__ out, const int* __restrict__ degd,
                                const float* __restrict__ b, int n) {
    int t = blockIdx.x * blockDim.x + threadIdx.x;
    if (t < n * 32) {
        int row = t >> 5;
        int col = t & 31;
        int d = degd[row];
        float nrm = (d > 0) ? rsqrtf((float)d) : 0.f;
        out[t] = out[t] * nrm + b[col];
    }
}

extern "C" void kernel_launch(void* const* d_in, const int* in_sizes, int n_in,
                              void* d_out, int out_size, void* d_ws, size_t ws_size,
                              hipStream_t stream) {
    const float* x  = (const float*)d_in[0];
    const int*   ei = (const int*)d_in[1];
    const float* W  = (const float*)d_in[2];
    const float* bb = (const float*)d_in[3];
    float* out = (float*)d_out;

    const int n = in_sizes[0] / DIN;   // 100000
    const int E = in_sizes[1] / 2;     // 1600000
    const int* src = ei;
    const int* dst = ei + E;

    const int NB = (n + BINW - 1) >> BINSHIFT;

    // Workspace layout (regions time-shared):
    //   B: binnedD (int2 E)  --later-->  h (float n*32)
    //   A: binnedS (int E)   --later-->  esrc (int E)
    //   degs[n] | offs[n+1] | gcntS[256] | gcntD[256] | baseS[257] | baseD[257]
    //   | curS[256] | curD[256]
    char* p = (char*)d_ws;
    size_t szB = (size_t)E * sizeof(int2);
    size_t szH = (size_t)n * DOUT * sizeof(float);
    if (szH > szB) szB = szH;
    int2*  binnedD = (int2*)p;
    float* h       = (float*)p;           p += szB;
    int*   binnedS = (int*)p;
    int*   esrc    = (int*)p;             p += (size_t)E * sizeof(int);
    int*   degs    = (int*)p;             p += (size_t)n * sizeof(int);
    int*   offs    = (int*)p;             p += (size_t)(n + 1) * sizeof(int);
    int*   gcntS   = (int*)p;             p += NBMAX * sizeof(int);
    int*   gcntD   = (int*)p;             p += NBMAX * sizeof(int);
    int*   baseS   = (int*)p;             p += (NBMAX + 1) * sizeof(int);
    int*   baseD   = (int*)p;             p += (NBMAX + 1) * sizeof(int);
    int*   curS    = (int*)p;             p += NBMAX * sizeof(int);
    int*   curD    = (int*)p;             p += NBMAX * sizeof(int);
    size_t needed = (size_t)(p - (char*)d_ws);

    const int partBlocks = (E + 256 * PK - 1) / (256 * PK);

    if (NB <= NBMAX && ws_size >= needed) {
        hipMemsetAsync(gcntS, 0, 2 * NBMAX * sizeof(int), stream);
        hist_coarse_kernel<<<512, 256, 0, stream>>>(src, dst, E, gcntS, gcntD);
        scan_coarse_kernel<<<1, 256, 0, stream>>>(gcntS, gcntD, baseS, baseD,
                                                  curS, curD, offs, NB, n, E);
        partitionS_kernel<<<partBlocks, 256, 0, stream>>>(src, E, curS, binnedS);
        bin_count_src_kernel<<<NB, 256, 0, stream>>>(binnedS, baseS, degs, n);
        partitionD_kernel<<<partBlocks, 256, 0, stream>>>(src, dst, E, curD, binnedD);
        bin_csr_kernel<<<NB, 256, 0, stream>>>(binnedD, baseD, offs, esrc, n);
        transform_kernel<<<(n + 7) / 8, 256, 0, stream>>>(x, W, degs, h, n);
        aggregate_kernel<<<(n * 64 + 255) / 256, 256, 0, stream>>>(offs, esrc, h, bb, out, n);
    } else {
        // Fallback: atomic path (h | degs | offs-as-degd).
        int* degd = offs;
        hipMemsetAsync(degs, 0, (size_t)(2 * n + 1) * sizeof(int), stream);
        hipMemsetAsync(d_out, 0, (size_t)out_size * sizeof(float), stream);
        deg_kernel<<<(E + 255) / 256, 256, 0, stream>>>(src, dst, degs, degd, E);
        transform_kernel<<<(n + 7) / 8, 256, 0, stream>>>(x, W, degs, h, n);
        long long st = (long long)E * 8;
        scatter_kernel<<<(int)((st + 255) / 256), 256, 0, stream>>>(src, dst, h, out, E);
        finalize_kernel<<<(n * 32 + 255) / 256, 256, 0, stream>>>(out, degd, bb, n);
    }
}

// Round 4
// 174.541 us; speedup vs baseline: 4.6403x; 1.0917x over previous
//
#include <hip/hip_runtime.h>
#include <hip/hip_bf16.h>

#define DIN 32
#define DOUT 32
#define NBMAX 256     // max coarse bins
#define BINSHIFT 9    // 512 nodes per bin
#define BINW 512
#define PK 16         // edges per thread in partition kernels (block covers 4096)
#define SRCBITS 17    // packed-entry src field width (n must be <= 1<<17)

__device__ __forceinline__ float bf_lo(unsigned v) { return __uint_as_float(v << 16); }
__device__ __forceinline__ float bf_hi(unsigned v) { return __uint_as_float(v & 0xffff0000u); }

// ---------------------------------------------------------------------------
// Coarse histograms of src and dst (bin = key >> BINSHIFT) in one read pass.
// ---------------------------------------------------------------------------
__global__ void hist_coarse_kernel(const int* __restrict__ src, const int* __restrict__ dst,
                                   int E, int* __restrict__ gcntS, int* __restrict__ gcntD) {
    __shared__ int hS[NBMAX], hD[NBMAX];
    for (int i = threadIdx.x; i < NBMAX; i += 256) { hS[i] = 0; hD[i] = 0; }
    __syncthreads();
    int stride = gridDim.x * blockDim.x;
    for (int e = blockIdx.x * blockDim.x + threadIdx.x; e < E; e += stride) {
        atomicAdd(&hS[src[e] >> BINSHIFT], 1);
        atomicAdd(&hD[dst[e] >> BINSHIFT], 1);
    }
    __syncthreads();
    for (int i = threadIdx.x; i < NBMAX; i += 256) {
        if (hS[i]) atomicAdd(&gcntS[i], hS[i]);
        if (hD[i]) atomicAdd(&gcntD[i], hD[i]);
    }
}

// ---------------------------------------------------------------------------
// Exclusive scan of both coarse histograms (single block); inits cursors.
// ---------------------------------------------------------------------------
__global__ void scan_coarse_kernel(const int* __restrict__ gcntS, const int* __restrict__ gcntD,
                                   int* __restrict__ baseS, int* __restrict__ baseD,
                                   int* __restrict__ curS, int* __restrict__ curD,
                                   int* __restrict__ offs, int NB, int n, int E) {
    __shared__ int s1[256], s2[256];
    int t = threadIdx.x;
    int a = (t < NB) ? gcntS[t] : 0;
    int c = (t < NB) ? gcntD[t] : 0;
    s1[t] = a; s2[t] = c;
    for (int o = 1; o < 256; o <<= 1) {
        __syncthreads();
        int x = (t >= o) ? s1[t - o] : 0;
        int y = (t >= o) ? s2[t - o] : 0;
        __syncthreads();
        s1[t] += x; s2[t] += y;
    }
    __syncthreads();
    if (t < NB) {
        baseS[t] = s1[t] - a; curS[t] = s1[t] - a;
        baseD[t] = s2[t] - c; curD[t] = s2[t] - c;
    }
    if (t == 0) { baseS[NB] = E; baseD[NB] = E; offs[n] = E; }
}

// ---------------------------------------------------------------------------
// Partition src values into coarse bins (key = payload = src).
// ---------------------------------------------------------------------------
__global__ void partitionS_kernel(const int* __restrict__ src, int E,
                                  int* __restrict__ curS, int* __restrict__ binned) {
    __shared__ int cnt[NBMAX];
    __shared__ int base[NBMAX];
    for (int i = threadIdx.x; i < NBMAX; i += 256) cnt[i] = 0;
    __syncthreads();
    int base_e = blockIdx.x * (256 * PK);
    int v[PK], rk[PK];
#pragma unroll
    for (int i = 0; i < PK; ++i) {
        int e = base_e + i * 256 + threadIdx.x;
        if (e < E) { v[i] = src[e]; rk[i] = atomicAdd(&cnt[v[i] >> BINSHIFT], 1); }
        else v[i] = -1;
    }
    __syncthreads();
    for (int i = threadIdx.x; i < NBMAX; i += 256) {
        int c = cnt[i];
        base[i] = c ? atomicAdd(&curS[i], c) : 0;
    }
    __syncthreads();
#pragma unroll
    for (int i = 0; i < PK; ++i)
        if (v[i] >= 0) binned[base[v[i] >> BINSHIFT] + rk[i]] = v[i];
}

// ---------------------------------------------------------------------------
// Partition edges into coarse bins keyed by dst; packed payload:
// ((dst & 511) << SRCBITS) | src   (requires n <= 1<<SRCBITS).
// ---------------------------------------------------------------------------
__global__ void partitionD_kernel(const int* __restrict__ src, const int* __restrict__ dst,
                                  int E, int* __restrict__ curD, int* __restrict__ binned) {
    __shared__ int cnt[NBMAX];
    __shared__ int base[NBMAX];
    for (int i = threadIdx.x; i < NBMAX; i += 256) cnt[i] = 0;
    __syncthreads();
    int base_e = blockIdx.x * (256 * PK);
    int vp[PK], vb[PK], rk[PK];
#pragma unroll
    for (int i = 0; i < PK; ++i) {
        int e = base_e + i * 256 + threadIdx.x;
        if (e < E) {
            int d = dst[e];
            vb[i] = d >> BINSHIFT;
            vp[i] = ((d & (BINW - 1)) << SRCBITS) | src[e];
            rk[i] = atomicAdd(&cnt[vb[i]], 1);
        } else vb[i] = -1;
    }
    __syncthreads();
    for (int i = threadIdx.x; i < NBMAX; i += 256) {
        int c = cnt[i];
        base[i] = c ? atomicAdd(&curD[i], c) : 0;
    }
    __syncthreads();
#pragma unroll
    for (int i = 0; i < PK; ++i)
        if (vb[i] >= 0) binned[base[vb[i]] + rk[i]] = vp[i];
}

// ---------------------------------------------------------------------------
// Per-bin src-degree count (LDS counters, bin spans 512 nodes).
// ---------------------------------------------------------------------------
__global__ void bin_count_src_kernel(const int* __restrict__ binned, const int* __restrict__ baseS,
                                     int* __restrict__ degs, int n) {
    __shared__ int cnt[BINW];
    int b = blockIdx.x;
    int beg = baseS[b], end = baseS[b + 1];
    int lo = b << BINSHIFT;
    int t = threadIdx.x;
    cnt[t] = 0; cnt[t + 256] = 0;
    __syncthreads();
    for (int e = beg + t; e < end; e += 256) atomicAdd(&cnt[binned[e] - lo], 1);
    __syncthreads();
    for (int i = t; i < BINW; i += 256) {
        int node = lo + i;
        if (node < n) degs[node] = cnt[i];
    }
}

// ---------------------------------------------------------------------------
// Per-bin CSR from packed entries: count, LDS scan, write offs, scatter esrc.
// ---------------------------------------------------------------------------
__global__ void bin_csr_kernel(const int* __restrict__ binned, const int* __restrict__ baseD,
                               int* __restrict__ offs, int* __restrict__ esrc, int n) {
    __shared__ int cnt[BINW];
    __shared__ int pscan[256];
    int b = blockIdx.x;
    int beg = baseD[b], end = baseD[b + 1];
    int lo = b << BINSHIFT;
    int t = threadIdx.x;
    cnt[t] = 0; cnt[t + 256] = 0;
    __syncthreads();
    for (int e = beg + t; e < end; e += 256)
        atomicAdd(&cnt[((unsigned)binned[e]) >> SRCBITS], 1);
    __syncthreads();
    int c0 = cnt[2 * t], c1 = cnt[2 * t + 1];
    int pair = c0 + c1;
    pscan[t] = pair;
    for (int o = 1; o < 256; o <<= 1) {
        __syncthreads();
        int x = (t >= o) ? pscan[t - o] : 0;
        __syncthreads();
        pscan[t] += x;
    }
    __syncthreads();
    int excl = pscan[t] - pair;
    int off0 = excl, off1 = excl + c0;
    int n0 = lo + 2 * t, n1 = n0 + 1;
    if (n0 < n) offs[n0] = beg + off0;
    if (n1 < n) offs[n1] = beg + off1;
    cnt[2 * t] = off0; cnt[2 * t + 1] = off1;   // become cursors
    __syncthreads();
    for (int e = beg + t; e < end; e += 256) {
        unsigned p = (unsigned)binned[e];
        int r = atomicAdd(&cnt[p >> SRCBITS], 1);
        esrc[beg + r] = (int)(p & ((1u << SRCBITS) - 1));
    }
}

// ---------------------------------------------------------------------------
// h = (x * norm_src) @ W, output bf16.  Block = 256 = 8 rows x 32 cols.
// ---------------------------------------------------------------------------
__global__ void transform_bf16_kernel(const float* __restrict__ x, const float* __restrict__ W,
                                      const int* __restrict__ degs,
                                      __hip_bfloat16* __restrict__ h, int n) {
    __shared__ float Ws[32][33];
    __shared__ float xs[8][32];
    int col = threadIdx.x & 31;
    int r   = threadIdx.x >> 5;

    for (int i = threadIdx.x; i < 32 * 32; i += 256) Ws[i >> 5][i & 31] = W[i];
    int row = blockIdx.x * 8 + r;
    xs[r][col] = (row < n) ? x[row * 32 + col] : 0.f;
    __syncthreads();

    if (row < n) {
        float acc = 0.f;
#pragma unroll
        for (int k = 0; k < 32; ++k) acc += xs[r][k] * Ws[k][col];
        int d = degs[row];
        float nrm = (d > 0) ? rsqrtf((float)d) : 0.f;
        h[row * 32 + col] = __float2bfloat16(acc * nrm);
    }
}

// ---------------------------------------------------------------------------
// Aggregate: one wave per dst node. lane = (pair p in [0,16), group g in [0,4)).
// Each lane gathers a uint (2 bf16 feats); 4 edges in flight + 2-unroll.
// ---------------------------------------------------------------------------
__global__ void aggregate_kernel(const int* __restrict__ offs, const int* __restrict__ esrc,
                                 const unsigned int* __restrict__ hb,
                                 const float* __restrict__ b, float* __restrict__ out, int n) {
    int node = (blockIdx.x * blockDim.x + threadIdx.x) >> 6;
    if (node >= n) return;
    int lane = threadIdx.x & 63;
    int p = lane & 15;   // feature pair
    int g = lane >> 4;   // edge group

    int beg = offs[node];
    int end = offs[node + 1];

    float a0 = 0.f, a1 = 0.f, a2 = 0.f, a3 = 0.f;
    int k = beg + g;
    for (; k + 4 < end; k += 8) {
        unsigned v0 = hb[(size_t)esrc[k] * 16 + p];
        unsigned v1 = hb[(size_t)esrc[k + 4] * 16 + p];
        a0 += bf_lo(v0); a1 += bf_hi(v0);
        a2 += bf_lo(v1); a3 += bf_hi(v1);
    }
    if (k < end) {
        unsigned v = hb[(size_t)esrc[k] * 16 + p];
        a0 += bf_lo(v); a1 += bf_hi(v);
    }
    a0 += a2; a1 += a3;
    a0 += __shfl_xor(a0, 16); a1 += __shfl_xor(a1, 16);
    a0 += __shfl_xor(a0, 32); a1 += __shfl_xor(a1, 32);

    if (g == 0) {
        int d = end - beg;
        float nrm = (d > 0) ? rsqrtf((float)d) : 0.f;
        float2 bv = *reinterpret_cast<const float2*>(&b[2 * p]);
        float2 r;
        r.x = a0 * nrm + bv.x;
        r.y = a1 * nrm + bv.y;
        *reinterpret_cast<float2*>(&out[(size_t)node * 32 + 2 * p]) = r;
    }
}

// ---------------------------------------------------------------------------
// Fallback (atomic) path kernels — only if workspace too small / n too large.
// ---------------------------------------------------------------------------
__global__ void deg_kernel(const int* __restrict__ src, const int* __restrict__ dst,
                           int* __restrict__ degs, int* __restrict__ degd, int E) {
    int i = blockIdx.x * blockDim.x + threadIdx.x;
    if (i < E) {
        atomicAdd(&degs[src[i]], 1);
        atomicAdd(&degd[dst[i]], 1);
    }
}

__global__ void transform_f32_kernel(const float* __restrict__ x, const float* __restrict__ W,
                                     const int* __restrict__ degs, float* __restrict__ h, int n) {
    __shared__ float Ws[32][33];
    __shared__ float xs[8][32];
    int col = threadIdx.x & 31;
    int r   = threadIdx.x >> 5;
    for (int i = threadIdx.x; i < 32 * 32; i += 256) Ws[i >> 5][i & 31] = W[i];
    int row = blockIdx.x * 8 + r;
    xs[r][col] = (row < n) ? x[row * 32 + col] : 0.f;
    __syncthreads();
    if (row < n) {
        float acc = 0.f;
#pragma unroll
        for (int k = 0; k < 32; ++k) acc += xs[r][k] * Ws[k][col];
        int d = degs[row];
        float nrm = (d > 0) ? rsqrtf((float)d) : 0.f;
        h[row * 32 + col] = acc * nrm;
    }
}

__global__ void scatter_kernel(const int* __restrict__ src, const int* __restrict__ dst,
                               const float* __restrict__ h, float* __restrict__ out, int E) {
    int t = blockIdx.x * blockDim.x + threadIdx.x;
    int e = t >> 3;
    int q = t & 7;
    if (e < E) {
        int s = src[e];
        int d = dst[e];
        const float4 v = *reinterpret_cast<const float4*>(&h[s * 32 + q * 4]);
        float* o = &out[d * 32 + q * 4];
        atomicAdd(o + 0, v.x);
        atomicAdd(o + 1, v.y);
        atomicAdd(o + 2, v.z);
        atomicAdd(o + 3, v.w);
    }
}

__global__ void finalize_kernel(float* __restrict__ out, const int* __restrict__ degd,
                                const float* __restrict__ b, int n) {
    int t = blockIdx.x * blockDim.x + threadIdx.x;
    if (t < n * 32) {
        int row = t >> 5;
        int col = t & 31;
        int d = degd[row];
        float nrm = (d > 0) ? rsqrtf((float)d) : 0.f;
        out[t] = out[t] * nrm + b[col];
    }
}

extern "C" void kernel_launch(void* const* d_in, const int* in_sizes, int n_in,
                              void* d_out, int out_size, void* d_ws, size_t ws_size,
                              hipStream_t stream) {
    const float* x  = (const float*)d_in[0];
    const int*   ei = (const int*)d_in[1];
    const float* W  = (const float*)d_in[2];
    const float* bb = (const float*)d_in[3];
    float* out = (float*)d_out;

    const int n = in_sizes[0] / DIN;   // 100000
    const int E = in_sizes[1] / 2;     // 1600000
    const int* src = ei;
    const int* dst = ei + E;

    const int NB = (n + BINW - 1) >> BINSHIFT;

    // Workspace layout (regions time-shared):
    //   B: binnedD (int E)  --later-->  h (bf16 n*32)
    //   A: binnedS (int E)  --later-->  esrc (int E)
    //   degs[n] | offs[n+1] | gcntS | gcntD | baseS | baseD | curS | curD
    char* p0 = (char*)d_ws;
    char* p = p0;
    size_t szB = (size_t)E * sizeof(int);
    size_t szH = (size_t)n * DOUT * sizeof(__hip_bfloat16);
    if (szH > szB) szB = szH;
    szB = (szB + 15) & ~(size_t)15;
    int*   binnedD = (int*)p;
    __hip_bfloat16* h = (__hip_bfloat16*)p;   p += szB;
    int*   binnedS = (int*)p;
    int*   esrc    = (int*)p;                 p += (size_t)E * sizeof(int);
    int*   degs    = (int*)p;                 p += (size_t)n * sizeof(int);
    int*   offs    = (int*)p;                 p += (size_t)(n + 1) * sizeof(int);
    int*   gcntS   = (int*)p;                 p += NBMAX * sizeof(int);
    int*   gcntD   = (int*)p;                 p += NBMAX * sizeof(int);
    int*   baseS   = (int*)p;                 p += (NBMAX + 1) * sizeof(int);
    int*   baseD   = (int*)p;                 p += (NBMAX + 1) * sizeof(int);
    int*   curS    = (int*)p;                 p += NBMAX * sizeof(int);
    int*   curD    = (int*)p;                 p += NBMAX * sizeof(int);
    size_t needed = (size_t)(p - p0);

    const int partBlocks = (E + 256 * PK - 1) / (256 * PK);

    if (NB <= NBMAX && n <= (1 << SRCBITS) && ws_size >= needed) {
        hipMemsetAsync(gcntS, 0, 2 * NBMAX * sizeof(int), stream);
        hist_coarse_kernel<<<512, 256, 0, stream>>>(src, dst, E, gcntS, gcntD);
        scan_coarse_kernel<<<1, 256, 0, stream>>>(gcntS, gcntD, baseS, baseD,
                                                  curS, curD, offs, NB, n, E);
        partitionS_kernel<<<partBlocks, 256, 0, stream>>>(src, E, curS, binnedS);
        bin_count_src_kernel<<<NB, 256, 0, stream>>>(binnedS, baseS, degs, n);
        partitionD_kernel<<<partBlocks, 256, 0, stream>>>(src, dst, E, curD, binnedD);
        bin_csr_kernel<<<NB, 256, 0, stream>>>(binnedD, baseD, offs, esrc, n);
        transform_bf16_kernel<<<(n + 7) / 8, 256, 0, stream>>>(x, W, degs, h, n);
        aggregate_kernel<<<(n * 64 + 255) / 256, 256, 0, stream>>>(
            offs, esrc, (const unsigned int*)h, bb, out, n);
    } else {
        // Fallback: atomic path. Layout: hf (f32 n*32) | degs[n] | degd[n]
        float* hf   = (float*)d_ws;
        int*   dgs  = (int*)(hf + (size_t)n * DOUT);
        int*   degd = dgs + n;
        hipMemsetAsync(dgs, 0, (size_t)2 * n * sizeof(int), stream);
        hipMemsetAsync(d_out, 0, (size_t)out_size * sizeof(float), stream);
        deg_kernel<<<(E + 255) / 256, 256, 0, stream>>>(src, dst, dgs, degd, E);
        transform_f32_kernel<<<(n + 7) / 8, 256, 0, stream>>>(x, W, dgs, hf, n);
        long long st = (long long)E * 8;
        scatter_kernel<<<(int)((st + 255) / 256), 256, 0, stream>>>(src, dst, hf, out, E);
        finalize_kernel<<<(n * 32 + 255) / 256, 256, 0, stream>>>(out, degd, bb, n);
    }
}

// Round 5
// 141.135 us; speedup vs baseline: 5.7386x; 1.2367x over previous
//
#include <hip/hip_runtime.h>
#include <hip/hip_bf16.h>

#define DIN 32
#define DOUT 32
#define NBMAX 256     // max coarse bins
#define BINSHIFT 9    // 512 nodes per bin
#define BINW 512
#define PK 16         // edges per thread in fused partition (block covers 4096)
#define SRCBITS 17    // packed-entry src field width (n must be <= 1<<17)

__device__ __forceinline__ float bf_lo(unsigned v) { return __uint_as_float(v << 16); }
__device__ __forceinline__ float bf_hi(unsigned v) { return __uint_as_float(v & 0xffff0000u); }
__device__ __forceinline__ unsigned f2bf_rne(float f) {
    unsigned u = __float_as_uint(f);
    return (u + 0x7fffu + ((u >> 16) & 1u)) >> 16;
}

// ---------------------------------------------------------------------------
// Coarse histograms of src and dst (bin = key >> BINSHIFT) in one read pass.
// ---------------------------------------------------------------------------
__global__ void hist_coarse_kernel(const int* __restrict__ src, const int* __restrict__ dst,
                                   int E, int* __restrict__ gcntS, int* __restrict__ gcntD) {
    __shared__ int hS[NBMAX], hD[NBMAX];
    for (int i = threadIdx.x; i < NBMAX; i += 256) { hS[i] = 0; hD[i] = 0; }
    __syncthreads();
    int stride = gridDim.x * blockDim.x;
    for (int e = blockIdx.x * blockDim.x + threadIdx.x; e < E; e += stride) {
        atomicAdd(&hS[src[e] >> BINSHIFT], 1);
        atomicAdd(&hD[dst[e] >> BINSHIFT], 1);
    }
    __syncthreads();
    for (int i = threadIdx.x; i < NBMAX; i += 256) {
        if (hS[i]) atomicAdd(&gcntS[i], hS[i]);
        if (hD[i]) atomicAdd(&gcntD[i], hD[i]);
    }
}

// ---------------------------------------------------------------------------
// Exclusive scan of both coarse histograms (single block); inits cursors.
// ---------------------------------------------------------------------------
__global__ void scan_coarse_kernel(const int* __restrict__ gcntS, const int* __restrict__ gcntD,
                                   int* __restrict__ baseS, int* __restrict__ baseD,
                                   int* __restrict__ curS, int* __restrict__ curD,
                                   int* __restrict__ offs, int NB, int n, int E) {
    __shared__ int s1[256], s2[256];
    int t = threadIdx.x;
    int a = (t < NB) ? gcntS[t] : 0;
    int c = (t < NB) ? gcntD[t] : 0;
    s1[t] = a; s2[t] = c;
    for (int o = 1; o < 256; o <<= 1) {
        __syncthreads();
        int x = (t >= o) ? s1[t - o] : 0;
        int y = (t >= o) ? s2[t - o] : 0;
        __syncthreads();
        s1[t] += x; s2[t] += y;
    }
    __syncthreads();
    if (t < NB) {
        baseS[t] = s1[t] - a; curS[t] = s1[t] - a;
        baseD[t] = s2[t] - c; curD[t] = s2[t] - c;
    }
    if (t == 0) { baseS[NB] = E; baseD[NB] = E; offs[n] = E; }
}

// ---------------------------------------------------------------------------
// Fused partition: one read of (src,dst); writes
//   binnedS: src values binned by src>>BINSHIFT
//   binnedD: packed ((dst&511)<<SRCBITS)|src binned by dst>>BINSHIFT
// ---------------------------------------------------------------------------
__global__ void partition_both_kernel(const int* __restrict__ src, const int* __restrict__ dst,
                                      int E, int* __restrict__ curS, int* __restrict__ curD,
                                      int* __restrict__ binnedS, int* __restrict__ binnedD) {
    __shared__ int cntS[NBMAX], cntD[NBMAX];
    __shared__ int basS[NBMAX], basD[NBMAX];
    for (int i = threadIdx.x; i < NBMAX; i += 256) { cntS[i] = 0; cntD[i] = 0; }
    __syncthreads();
    int base_e = blockIdx.x * (256 * PK);
    int vs[PK], vd[PK], rkS[PK], rkD[PK];
#pragma unroll
    for (int i = 0; i < PK; ++i) {
        int e = base_e + i * 256 + threadIdx.x;
        if (e < E) {
            int s = src[e], d = dst[e];
            vs[i] = s; vd[i] = d;
            rkS[i] = atomicAdd(&cntS[s >> BINSHIFT], 1);
            rkD[i] = atomicAdd(&cntD[d >> BINSHIFT], 1);
        } else vs[i] = -1;
    }
    __syncthreads();
    for (int i = threadIdx.x; i < NBMAX; i += 256) {
        int c = cntS[i];
        basS[i] = c ? atomicAdd(&curS[i], c) : 0;
        c = cntD[i];
        basD[i] = c ? atomicAdd(&curD[i], c) : 0;
    }
    __syncthreads();
#pragma unroll
    for (int i = 0; i < PK; ++i) {
        if (vs[i] >= 0) {
            binnedS[basS[vs[i] >> BINSHIFT] + rkS[i]] = vs[i];
            binnedD[basD[vd[i] >> BINSHIFT] + rkD[i]] =
                ((vd[i] & (BINW - 1)) << SRCBITS) | vs[i];
        }
    }
}

// ---------------------------------------------------------------------------
// Fused bin pass: blocks [0,NB) count src degrees; blocks [NB,2NB) build CSR.
// ---------------------------------------------------------------------------
__global__ void bins_fused_kernel(const int* __restrict__ binnedS, const int* __restrict__ baseS,
                                  const int* __restrict__ binnedD, const int* __restrict__ baseD,
                                  int* __restrict__ degs, int* __restrict__ offs,
                                  int* __restrict__ esrc, int n, int NB) {
    __shared__ int cnt[BINW];
    __shared__ int pscan[256];
    int t = threadIdx.x;
    if ((int)blockIdx.x < NB) {
        int b = blockIdx.x;
        int beg = baseS[b], end = baseS[b + 1];
        int lo = b << BINSHIFT;
        cnt[t] = 0; cnt[t + 256] = 0;
        __syncthreads();
        for (int e = beg + t; e < end; e += 256) atomicAdd(&cnt[binnedS[e] - lo], 1);
        __syncthreads();
        for (int i = t; i < BINW; i += 256) {
            int node = lo + i;
            if (node < n) degs[node] = cnt[i];
        }
    } else {
        int b = blockIdx.x - NB;
        int beg = baseD[b], end = baseD[b + 1];
        int lo = b << BINSHIFT;
        cnt[t] = 0; cnt[t + 256] = 0;
        __syncthreads();
        for (int e = beg + t; e < end; e += 256)
            atomicAdd(&cnt[((unsigned)binnedD[e]) >> SRCBITS], 1);
        __syncthreads();
        int c0 = cnt[2 * t], c1 = cnt[2 * t + 1];
        int pair = c0 + c1;
        pscan[t] = pair;
        for (int o = 1; o < 256; o <<= 1) {
            __syncthreads();
            int x = (t >= o) ? pscan[t - o] : 0;
            __syncthreads();
            pscan[t] += x;
        }
        __syncthreads();
        int excl = pscan[t] - pair;
        int off0 = excl, off1 = excl + c0;
        int n0 = lo + 2 * t, n1 = n0 + 1;
        if (n0 < n) offs[n0] = beg + off0;
        if (n1 < n) offs[n1] = beg + off1;
        cnt[2 * t] = off0; cnt[2 * t + 1] = off1;   // become cursors
        __syncthreads();
        for (int e = beg + t; e < end; e += 256) {
            unsigned p = (unsigned)binnedD[e];
            int r = atomicAdd(&cnt[p >> SRCBITS], 1);
            esrc[beg + r] = (int)(p & ((1u << SRCBITS) - 1));
        }
    }
}

// ---------------------------------------------------------------------------
// h = (x * norm_src) @ W, packed bf16x2 output. 256 = 16 rows x 16 pairs.
// ---------------------------------------------------------------------------
__global__ void transform_bf16_kernel(const float* __restrict__ x, const float* __restrict__ W,
                                      const int* __restrict__ degs,
                                      unsigned* __restrict__ h, int n) {
    __shared__ float Ws[32][33];
    __shared__ float xs[16][32];
    int pr = threadIdx.x & 15;
    int r  = threadIdx.x >> 4;

    for (int i = threadIdx.x; i < 32 * 32; i += 256) Ws[i >> 5][i & 31] = W[i];
    int row = blockIdx.x * 16 + r;
    if (row < n) {
        float2 xv = *reinterpret_cast<const float2*>(&x[(size_t)row * 32 + 2 * pr]);
        xs[r][2 * pr] = xv.x; xs[r][2 * pr + 1] = xv.y;
    }
    __syncthreads();

    if (row < n) {
        float a0 = 0.f, a1 = 0.f;
#pragma unroll
        for (int k = 0; k < 32; ++k) {
            float xv = xs[r][k];
            a0 += xv * Ws[k][2 * pr];
            a1 += xv * Ws[k][2 * pr + 1];
        }
        int d = degs[row];
        float nrm = (d > 0) ? rsqrtf((float)d) : 0.f;
        h[(size_t)row * 16 + pr] = f2bf_rne(a0 * nrm) | (f2bf_rne(a1 * nrm) << 16);
    }
}

// ---------------------------------------------------------------------------
// Aggregate: one wave per dst node. lane = (quad q in [0,8), group g in [0,8)).
// uint2 gathers: 8 lanes cover a 64B row; 8 edges per wave-instr, 16 in flight.
// ---------------------------------------------------------------------------
__global__ void aggregate_kernel(const int* __restrict__ offs, const int* __restrict__ esrc,
                                 const uint2* __restrict__ hb,
                                 const float* __restrict__ bias, float* __restrict__ out, int n) {
    int node = (blockIdx.x * blockDim.x + threadIdx.x) >> 6;
    if (node >= n) return;
    int lane = threadIdx.x & 63;
    int q = lane & 7;    // feature quad
    int g = lane >> 3;   // edge group

    int beg = offs[node];
    int end = offs[node + 1];

    float a0 = 0.f, a1 = 0.f, a2 = 0.f, a3 = 0.f;
    float b0 = 0.f, b1 = 0.f, b2 = 0.f, b3 = 0.f;
    int k = beg + g;
    for (; k + 8 < end; k += 16) {
        uint2 v0 = hb[(size_t)esrc[k] * 8 + q];
        uint2 v1 = hb[(size_t)esrc[k + 8] * 8 + q];
        a0 += bf_lo(v0.x); a1 += bf_hi(v0.x); a2 += bf_lo(v0.y); a3 += bf_hi(v0.y);
        b0 += bf_lo(v1.x); b1 += bf_hi(v1.x); b2 += bf_lo(v1.y); b3 += bf_hi(v1.y);
    }
    if (k < end) {
        uint2 v = hb[(size_t)esrc[k] * 8 + q];
        a0 += bf_lo(v.x); a1 += bf_hi(v.x); a2 += bf_lo(v.y); a3 += bf_hi(v.y);
    }
    a0 += b0; a1 += b1; a2 += b2; a3 += b3;
#pragma unroll
    for (int m = 8; m < 64; m <<= 1) {
        a0 += __shfl_xor(a0, m);
        a1 += __shfl_xor(a1, m);
        a2 += __shfl_xor(a2, m);
        a3 += __shfl_xor(a3, m);
    }

    if (g == 0) {
        int d = end - beg;
        float nrm = (d > 0) ? rsqrtf((float)d) : 0.f;
        float4 bv = *reinterpret_cast<const float4*>(&bias[4 * q]);
        float4 r;
        r.x = a0 * nrm + bv.x;
        r.y = a1 * nrm + bv.y;
        r.z = a2 * nrm + bv.z;
        r.w = a3 * nrm + bv.w;
        *reinterpret_cast<float4*>(&out[(size_t)node * 32 + 4 * q]) = r;
    }
}

// ---------------------------------------------------------------------------
// Fallback (atomic) path kernels — only if workspace too small / n too large.
// ---------------------------------------------------------------------------
__global__ void deg_kernel(const int* __restrict__ src, const int* __restrict__ dst,
                           int* __restrict__ degs, int* __restrict__ degd, int E) {
    int i = blockIdx.x * blockDim.x + threadIdx.x;
    if (i < E) {
        atomicAdd(&degs[src[i]], 1);
        atomicAdd(&degd[dst[i]], 1);
    }
}

__global__ void transform_f32_kernel(const float* __restrict__ x, const float* __restrict__ W,
                                     const int* __restrict__ degs, float* __restrict__ h, int n) {
    __shared__ float Ws[32][33];
    __shared__ float xs[8][32];
    int col = threadIdx.x & 31;
    int r   = threadIdx.x >> 5;
    for (int i = threadIdx.x; i < 32 * 32; i += 256) Ws[i >> 5][i & 31] = W[i];
    int row = blockIdx.x * 8 + r;
    xs[r][col] = (row < n) ? x[row * 32 + col] : 0.f;
    __syncthreads();
    if (row < n) {
        float acc = 0.f;
#pragma unroll
        for (int k = 0; k < 32; ++k) acc += xs[r][k] * Ws[k][col];
        int d = degs[row];
        float nrm = (d > 0) ? rsqrtf((float)d) : 0.f;
        h[row * 32 + col] = acc * nrm;
    }
}

__global__ void scatter_kernel(const int* __restrict__ src, const int* __restrict__ dst,
                               const float* __restrict__ h, float* __restrict__ out, int E) {
    int t = blockIdx.x * blockDim.x + threadIdx.x;
    int e = t >> 3;
    int q = t & 7;
    if (e < E) {
        int s = src[e];
        int d = dst[e];
        const float4 v = *reinterpret_cast<const float4*>(&h[s * 32 + q * 4]);
        float* o = &out[d * 32 + q * 4];
        atomicAdd(o + 0, v.x);
        atomicAdd(o + 1, v.y);
        atomicAdd(o + 2, v.z);
        atomicAdd(o + 3, v.w);
    }
}

__global__ void finalize_kernel(float* __restrict__ out, const int* __restrict__ degd,
                                const float* __restrict__ b, int n) {
    int t = blockIdx.x * blockDim.x + threadIdx.x;
    if (t < n * 32) {
        int row = t >> 5;
        int col = t & 31;
        int d = degd[row];
        float nrm = (d > 0) ? rsqrtf((float)d) : 0.f;
        out[t] = out[t] * nrm + b[col];
    }
}

extern "C" void kernel_launch(void* const* d_in, const int* in_sizes, int n_in,
                              void* d_out, int out_size, void* d_ws, size_t ws_size,
                              hipStream_t stream) {
    const float* x  = (const float*)d_in[0];
    const int*   ei = (const int*)d_in[1];
    const float* W  = (const float*)d_in[2];
    const float* bb = (const float*)d_in[3];
    float* out = (float*)d_out;

    const int n = in_sizes[0] / DIN;   // 100000
    const int E = in_sizes[1] / 2;     // 1600000
    const int* src = ei;
    const int* dst = ei + E;

    const int NB = (n + BINW - 1) >> BINSHIFT;

    // Workspace layout:
    //   R1: binnedD (int E)  --later-->  h (bf16 n*32)   [transform after bins_fused]
    //   R2: binnedS (int E)
    //   R3: esrc   (int E)   [must NOT alias binnedS/binnedD: bins_fused races]
    //   degs[n] | offs[n+1] | gcntS | gcntD | baseS | baseD | curS | curD
    char* p0 = (char*)d_ws;
    char* p = p0;
    size_t szR1 = (size_t)E * sizeof(int);
    size_t szH  = (size_t)n * DOUT * sizeof(__hip_bfloat16);
    if (szH > szR1) szR1 = szH;
    szR1 = (szR1 + 15) & ~(size_t)15;
    int*      binnedD = (int*)p;
    unsigned* h       = (unsigned*)p;         p += szR1;
    int*      binnedS = (int*)p;              p += (size_t)E * sizeof(int);
    int*      esrc    = (int*)p;              p += (size_t)E * sizeof(int);
    int*      degs    = (int*)p;              p += (size_t)n * sizeof(int);
    int*      offs    = (int*)p;              p += (size_t)(n + 1) * sizeof(int);
    int*      gcntS   = (int*)p;              p += NBMAX * sizeof(int);
    int*      gcntD   = (int*)p;              p += NBMAX * sizeof(int);
    int*      baseS   = (int*)p;              p += (NBMAX + 1) * sizeof(int);
    int*      baseD   = (int*)p;              p += (NBMAX + 1) * sizeof(int);
    int*      curS    = (int*)p;              p += NBMAX * sizeof(int);
    int*      curD    = (int*)p;              p += NBMAX * sizeof(int);
    size_t needed = (size_t)(p - p0);

    const int partBlocks = (E + 256 * PK - 1) / (256 * PK);

    if (NB <= NBMAX && n <= (1 << SRCBITS) && ws_size >= needed) {
        hipMemsetAsync(gcntS, 0, 2 * NBMAX * sizeof(int), stream);
        hist_coarse_kernel<<<512, 256, 0, stream>>>(src, dst, E, gcntS, gcntD);
        scan_coarse_kernel<<<1, 256, 0, stream>>>(gcntS, gcntD, baseS, baseD,
                                                  curS, curD, offs, NB, n, E);
        partition_both_kernel<<<partBlocks, 256, 0, stream>>>(src, dst, E, curS, curD,
                                                              binnedS, binnedD);
        bins_fused_kernel<<<2 * NB, 256, 0, stream>>>(binnedS, baseS, binnedD, baseD,
                                                      degs, offs, esrc, n, NB);
        transform_bf16_kernel<<<(n + 15) / 16, 256, 0, stream>>>(x, W, degs, h, n);
        aggregate_kernel<<<(n * 64 + 255) / 256, 256, 0, stream>>>(
            offs, esrc, (const uint2*)h, bb, out, n);
    } else {
        // Fallback: atomic path. Layout: hf (f32 n*32) | degs[n] | degd[n]
        float* hf   = (float*)d_ws;
        int*   dgs  = (int*)(hf + (size_t)n * DOUT);
        int*   degd = dgs + n;
        hipMemsetAsync(dgs, 0, (size_t)2 * n * sizeof(int), stream);
        hipMemsetAsync(d_out, 0, (size_t)out_size * sizeof(float), stream);
        deg_kernel<<<(E + 255) / 256, 256, 0, stream>>>(src, dst, dgs, degd, E);
        transform_f32_kernel<<<(n + 7) / 8, 256, 0, stream>>>(x, W, dgs, hf, n);
        long long st = (long long)E * 8;
        scatter_kernel<<<(int)((st + 255) / 256), 256, 0, stream>>>(src, dst, hf, out, E);
        finalize_kernel<<<(n * 32 + 255) / 256, 256, 0, stream>>>(out, degd, bb, n);
    }
}